// Round 13
// baseline (1453.673 us; speedup 1.0000x reference)
//
#include <hip/hip_runtime.h>
#include <hip/hip_bf16.h>
#include <math.h>

// Transformer forward, MI355X. Sizes fixed by the reference.
#define VSZ 32000
#define DSZ 384
#define HSZ 6
#define LSZ 6
#define FHSZ 1536
#define BSZ 38
#define SSZ 256
#define HDSZ 64
#define NROW (BSZ*SSZ)    // 9728
#define D3 (3*DSZ)        // 1152
#define NTB256 (VSZ/256)  // 125 logits col-tiles

typedef __bf16 bf16;
typedef __attribute__((ext_vector_type(8))) __bf16 bf16x8;
typedef __attribute__((ext_vector_type(4))) __bf16 bf16x4;
typedef __attribute__((ext_vector_type(4))) float f32x4;

__device__ __forceinline__ void gload16(const bf16* g, bf16* l) {
  __builtin_amdgcn_global_load_lds((const __attribute__((address_space(1))) void*)g,
                                   (__attribute__((address_space(3))) void*)l, 16, 0, 0);
}

// bijective XCD-chunked swizzle (m204)
__device__ __forceinline__ int xcd_swz(int orig, int nwg) {
  int q = nwg >> 3, r = nwg & 7;
  int xcd = orig & 7, lin = orig >> 3;
  return (xcd < r ? xcd*(q+1) : r*(q+1) + (xcd - r)*q) + lin;
}

// fast erf, Abramowitz-Stegun 7.1.26 (|err|<=1.5e-7, far below bf16 rounding)
__device__ __forceinline__ float fast_erf(float x) {
  float ax = fabsf(x);
  float t = 1.0f / fmaf(0.3275911f, ax, 1.0f);
  float p = fmaf(t, 1.061405429f, -1.453152027f);
  p = fmaf(p, t, 1.421413741f);
  p = fmaf(p, t, -0.284496736f);
  p = fmaf(p, t, 0.254829592f);
  float y = 1.0f - p*t*__expf(-ax*ax);
  return copysignf(y, x);
}

// ---------------- batched f32 -> bf16 weight convert (one launch) -----------
struct CvtDesc { const float* s0; bf16* d0; const float* s1; bf16* d1;
                 const float* s2; bf16* d2; const float* s3; bf16* d3;
                 const float* s4; bf16* d4; };
#define C0 663552   // Wqkv n4 end
#define C1 884736   // + Wo
#define C2 1769472  // + W1
#define C3 2654208  // + W2
#define C4 5726208  // + Wout
__global__ __launch_bounds__(256) void cvt_all(CvtDesc dd) {
  int i = blockIdx.x*256 + threadIdx.x;
  int st = gridDim.x*256;
  for (; i < C4; i += st) {
    const float* s; bf16* d; int o;
    if      (i < C0) { s = dd.s0; d = dd.d0; o = i; }
    else if (i < C1) { s = dd.s1; d = dd.d1; o = i - C0; }
    else if (i < C2) { s = dd.s2; d = dd.d2; o = i - C1; }
    else if (i < C3) { s = dd.s3; d = dd.d3; o = i - C2; }
    else             { s = dd.s4; d = dd.d4; o = i - C3; }
    f32x4 v = __builtin_nontemporal_load((const f32x4*)s + o);
    bf16x4 ov = { (bf16)v[0], (bf16)v[1], (bf16)v[2], (bf16)v[3] };
    *(bf16x4*)(d + 4*(size_t)o) = ov;
  }
}

// ---------------- positional-encoding table (256 x 384) ---------------------
__global__ __launch_bounds__(256) void pe_k(float* __restrict__ pe) {
  const float c = 2.0f/384.0f*13.287712379549449f; // *log2(10000)
  int i = blockIdx.x*256 + threadIdx.x;            // 384 blocks
  int s = i / DSZ, d = i - s*DSZ;
  int ii = d >> 1;
  float ang = (float)s * exp2f(-(float)ii * c);
  pe[i] = (d & 1) ? cosf(ang) : sinf(ang);
}

// ---------------- embedding + pos table (pure BW) ---------------------------
__global__ __launch_bounds__(256) void embed_k(const int* __restrict__ x,
    const float* __restrict__ emb, const float* __restrict__ pe,
    float* __restrict__ h, bf16* __restrict__ hb) {
  const float scale = 19.595917942265423f; // sqrt(384)
  int i4 = blockIdx.x*256 + threadIdx.x;
  int st = gridDim.x*256;
  for (; i4 < NROW*(DSZ/4); i4 += st) {
    int r = i4 / (DSZ/4), c4 = (i4 - r*(DSZ/4))*4;
    int tok = x[r];
    int s = r & (SSZ-1);
    f32x4 e = *((const f32x4*)(emb + (size_t)tok*DSZ + c4));
    f32x4 p = *((const f32x4*)(pe + (size_t)s*DSZ + c4));
    f32x4 v = { e[0]*scale + p[0], e[1]*scale + p[1],
                e[2]*scale + p[2], e[3]*scale + p[3] };
    *(f32x4*)(h + (size_t)i4*4) = v;
    bf16x4 o = { (bf16)v[0], (bf16)v[1], (bf16)v[2], (bf16)v[3] };
    *(bf16x4*)(hb + (size_t)i4*4) = o;
  }
}

// ---------------- 128x128 GEMM: C = A * B^T + bias (2-phase dbuf, T2 swz) ---
// MODE 1: bf16 out; 2: exact-GELU (fast_erf) then bf16 out.
template<int MODE>
__global__ __launch_bounds__(256) void gemm_bt(const bf16* __restrict__ A,
    const bf16* __restrict__ Bm, const float* __restrict__ bias,
    bf16* __restrict__ Cv, int N, int K) {
  __shared__ __align__(16) bf16 As[2][128*64];
  __shared__ __align__(16) bf16 Bs[2][128*64];
  const int tid = threadIdx.x;
  const int lane = tid & 63, wid = tid >> 6;

  const int GX = gridDim.x, GY = gridDim.y;
  int orig = blockIdx.y*GX + blockIdx.x;
  int swz = xcd_swz(orig, GX*GY);
  int by = swz / GX, bx = swz - (swz/GX)*GX;

  const int wm = (wid >> 1) * 64, wn = (wid & 1) * 64;
  const int lr = lane & 15, lk = (lane >> 4) * 8;
  const int sx = (lr & 7) * 8;  // per-lane XOR swizzle offset (elements)

  f32x4 acc[4][4];
  f32x4 zz = {0.f, 0.f, 0.f, 0.f};
#pragma unroll
  for (int m = 0; m < 4; ++m)
#pragma unroll
    for (int n = 0; n < 4; ++n) acc[m][n] = zz;

  const bf16* Ab = A + (size_t)by*128*K;
  const bf16* Bb = Bm + (size_t)bx*128*K;
  const int nk = K >> 6;

  auto STAGE = [&](int buf, int kt) {
#pragma unroll
    for (int c = 0; c < 4; ++c) {
      int chunk = c*256 + tid;
      int row = chunk >> 3, sub = chunk & 7;
      int scol = (sub ^ (row & 7)) * 8;   // pre-swizzled source chunk
      gload16(Ab + (size_t)row*K + kt*64 + scol, &As[buf][chunk*8]);
      gload16(Bb + (size_t)row*K + kt*64 + scol, &Bs[buf][chunk*8]);
    }
  };

  STAGE(0, 0);
  __syncthreads();
  int cur = 0;
  for (int kt = 0; kt < nk; ++kt) {
    if (kt + 1 < nk) STAGE(cur ^ 1, kt + 1);
#pragma unroll
    for (int kk = 0; kk < 2; ++kk) {
      bf16x8 af[4], bfr[4];
#pragma unroll
      for (int m = 0; m < 4; ++m)
        af[m] = *(const bf16x8*)(&As[cur][(wm + m*16 + lr)*64 + ((kk*32 + lk) ^ sx)]);
#pragma unroll
      for (int n = 0; n < 4; ++n)
        bfr[n] = *(const bf16x8*)(&Bs[cur][(wn + n*16 + lr)*64 + ((kk*32 + lk) ^ sx)]);
#pragma unroll
      for (int m = 0; m < 4; ++m)
#pragma unroll
        for (int n = 0; n < 4; ++n)
          acc[m][n] = __builtin_amdgcn_mfma_f32_16x16x32_bf16(af[m], bfr[n], acc[m][n], 0, 0, 0);
    }
    __syncthreads();
    cur ^= 1;
  }

  float bv[4];
#pragma unroll
  for (int n = 0; n < 4; ++n) bv[n] = bias[bx*128 + wn + n*16 + lr];
  const int r0 = (lane >> 4) * 4;
#pragma unroll
  for (int m = 0; m < 4; ++m) {
#pragma unroll
    for (int r = 0; r < 4; ++r) {
      size_t row = (size_t)by*128 + wm + m*16 + r0 + r;
#pragma unroll
      for (int n = 0; n < 4; ++n) {
        float v = acc[m][n][r] + bv[n];
        size_t ci = row*(size_t)N + (size_t)(bx*128 + wn + n*16 + lr);
        if (MODE == 1) Cv[ci] = (bf16)v;
        else {
          v = 0.5f*v*(1.0f + fast_erf(v*0.70710678118654752f));
          Cv[ci] = (bf16)v;
        }
      }
    }
  }
}

// ---------------- fused GEMM(+bias) + residual + LayerNorm ------------------
// C-tile = 64 rows x FULL N=384: one block owns complete output rows, so the
// LN row-reduce stays on-chip. BK=32, 2-phase dbuf, T2 swizzle (BK=32 form).
// 4 waves x (64 rows x 96 cols) = acc[4][6]. LDS 58 KB -> 2 blocks/CU.
// v = A*B^T + bias + h;  h = LN(v)*gamma+beta;  hb = bf16(h).
template<int K>
__global__ __launch_bounds__(256) void gemm_ln(const bf16* __restrict__ A,
    const bf16* __restrict__ Bm, const float* __restrict__ bias,
    const float* __restrict__ gamma, const float* __restrict__ beta,
    float* __restrict__ h, bf16* __restrict__ hb) {
  __shared__ __align__(16) bf16 As[2][64*32];    // 8 KB
  __shared__ __align__(16) bf16 Bs[2][384*32];   // 48 KB
  __shared__ float sm_s[4][64], sm_q[4][64];     // 2 KB
  const int tid = threadIdx.x;
  const int lane = tid & 63, wid = tid >> 6;
  const int by = xcd_swz(blockIdx.x, gridDim.x); // 152 blocks
  const int wn = wid * 96;                       // wave's 96-col slice
  const int lr = lane & 15, lk = (lane >> 4) * 8;

  f32x4 acc[4][6];
  f32x4 zz = {0.f, 0.f, 0.f, 0.f};
#pragma unroll
  for (int m = 0; m < 4; ++m)
#pragma unroll
    for (int n = 0; n < 6; ++n) acc[m][n] = zz;

  const bf16* Ab = A + (size_t)by*64*K;
  const int nk = K >> 5;

  // BK=32 swizzle: chunk (row,sub∈[0,4)) holds global col-chunk sub^((row>>1)&3)
  auto STAGE = [&](int buf, int kt) {
    { // A: 64x32 = 256 chunks -> 1/thread
      int row = tid >> 2, sub = tid & 3;
      int scol = (sub ^ ((row >> 1) & 3)) * 8;
      gload16(Ab + (size_t)row*K + kt*32 + scol, &As[buf][tid*8]);
    }
#pragma unroll
    for (int c = 0; c < 6; ++c) { // B: 384x32 = 1536 chunks -> 6/thread
      int chunk = c*256 + tid;
      int row = chunk >> 2, sub = chunk & 3;
      int scol = (sub ^ ((row >> 1) & 3)) * 8;
      gload16(Bm + (size_t)row*K + kt*32 + scol, &Bs[buf][chunk*8]);
    }
  };

  STAGE(0, 0);
  __syncthreads();
  int cur = 0;
  for (int kt = 0; kt < nk; ++kt) {
    if (kt + 1 < nk) STAGE(cur ^ 1, kt + 1);
    bf16x8 af[4], bfr[6];
#pragma unroll
    for (int m = 0; m < 4; ++m) {
      int row = m*16 + lr;
      af[m] = *(const bf16x8*)(&As[cur][row*32 + (lk ^ (((row >> 1) & 3)*8))]);
    }
#pragma unroll
    for (int n = 0; n < 6; ++n) {
      int row = wn + n*16 + lr;
      bfr[n] = *(const bf16x8*)(&Bs[cur][row*32 + (lk ^ (((row >> 1) & 3)*8))]);
    }
#pragma unroll
    for (int m = 0; m < 4; ++m)
#pragma unroll
      for (int n = 0; n < 6; ++n)
        acc[m][n] = __builtin_amdgcn_mfma_f32_16x16x32_bf16(af[m], bfr[n], acc[m][n], 0, 0, 0);
    __syncthreads();
    cur ^= 1;
  }

  float bv[6], gv[6], btv[6];
#pragma unroll
  for (int n = 0; n < 6; ++n) {
    int col = wn + n*16 + lr;
    bv[n] = bias[col]; gv[n] = gamma[col]; btv[n] = beta[col];
  }
  const int r0 = (lane >> 4) * 4;

  // v = acc + bias + residual (in place)
#pragma unroll
  for (int m = 0; m < 4; ++m)
#pragma unroll
    for (int r = 0; r < 4; ++r) {
      size_t row = (size_t)by*64 + m*16 + r0 + r;
#pragma unroll
      for (int n = 0; n < 6; ++n)
        acc[m][n][r] += bv[n] + h[row*DSZ + wn + n*16 + lr];
    }

  // per-row partial sum / sumsq over this wave's 96 cols
#pragma unroll
  for (int m = 0; m < 4; ++m)
#pragma unroll
    for (int r = 0; r < 4; ++r) {
      float s = 0.f, q = 0.f;
#pragma unroll
      for (int n = 0; n < 6; ++n) { float x = acc[m][n][r]; s += x; q += x*x; }
#pragma unroll
      for (int o = 1; o <= 8; o <<= 1) { s += __shfl_xor(s, o); q += __shfl_xor(q, o); }
      if (lr == 0) { sm_s[wid][m*16 + r0 + r] = s; sm_q[wid][m*16 + r0 + r] = q; }
    }
  __syncthreads();

#pragma unroll
  for (int m = 0; m < 4; ++m)
#pragma unroll
    for (int r = 0; r < 4; ++r) {
      const int rl = m*16 + r0 + r;
      float S = sm_s[0][rl] + sm_s[1][rl] + sm_s[2][rl] + sm_s[3][rl];
      float Q = sm_q[0][rl] + sm_q[1][rl] + sm_q[2][rl] + sm_q[3][rl];
      float mean = S * (1.0f/DSZ);
      float var = Q * (1.0f/DSZ) - mean*mean;
      float rstd = rsqrtf(var + 1e-5f);
      size_t row = (size_t)by*64 + rl;
#pragma unroll
      for (int n = 0; n < 6; ++n) {
        float outv = gv[n]*(acc[m][n][r] - mean)*rstd + btv[n];
        size_t ci = row*DSZ + wn + n*16 + lr;
        h[ci] = outv;
        hb[ci] = (bf16)outv;
      }
    }
}

// ---------------- 256x256 logits GEMM + fused LSE partials ------------------
// BK=32, 4 LDS buffers, 3-deep counted-vmcnt pipeline (T4).
__global__ __launch_bounds__(512, 2) void gemm256_lse(const bf16* __restrict__ A,
    const bf16* __restrict__ Bm, const float* __restrict__ bias,
    float* __restrict__ C, float* __restrict__ pmax, float* __restrict__ psum) {
  __shared__ __align__(16) bf16 As[4][256*32];   // 64 KB
  __shared__ __align__(16) bf16 Bs[4][256*32];   // 64 KB
  __shared__ float sm_m[4][256], sm_s[4][256];   // 8 KB
  const int K = DSZ, N = VSZ;
  const int tid = threadIdx.x;
  const int lane = tid & 63, wid = tid >> 6;

  const int GX = gridDim.x, GY = gridDim.y;   // (125, 38)
  int orig = blockIdx.y*GX + blockIdx.x;
  int swz = xcd_swz(orig, GX*GY);
  int bx = swz / GY, by = swz - (swz/GY)*GY;  // col-major: B-panel hot per XCD

  const int wm = (wid >> 2) * 128, wn = (wid & 3) * 64;
  const int lr = lane & 15, lk = (lane >> 4) * 8;  // lk in {0,8,16,24}

  f32x4 acc[8][4];
  f32x4 zz = {0.f, 0.f, 0.f, 0.f};
#pragma unroll
  for (int m = 0; m < 8; ++m)
#pragma unroll
    for (int n = 0; n < 4; ++n) acc[m][n] = zz;

  const bf16* Ab = A + (size_t)by*256*K;
  const bf16* Bb = Bm + (size_t)bx*256*K;
  const int nk = 12;  // K=384 / BK=32

  auto STAGE = [&](int buf, int kt) {
#pragma unroll
    for (int c = 0; c < 2; ++c) {
      int chunk = c*512 + tid;           // 1024 chunks = 256 rows x 4 sub
      int row = chunk >> 2, sub = chunk & 3;
      int scol = (sub ^ ((row >> 1) & 3)) * 8;   // inverse-swizzled source
      gload16(Ab + (size_t)row*K + kt*32 + scol, &As[buf][chunk*8]);
      gload16(Bb + (size_t)row*K + kt*32 + scol, &Bs[buf][chunk*8]);
    }
  };

  STAGE(0, 0); STAGE(1, 1); STAGE(2, 2);   // 12 loads/thread in flight
  for (int kt = 0; kt < nk; ++kt) {
    if (kt < nk - 2)      asm volatile("s_waitcnt vmcnt(8)" ::: "memory");
    else if (kt == nk-2)  asm volatile("s_waitcnt vmcnt(4)" ::: "memory");
    else                  asm volatile("s_waitcnt vmcnt(0)" ::: "memory");
    __builtin_amdgcn_s_barrier();
    __builtin_amdgcn_sched_barrier(0);   // rule 18: no ds_read hoist above bar
    const int buf = kt & 3;
    bf16x8 af[8], bfr[4];
#pragma unroll
    for (int n = 0; n < 4; ++n) {
      int row = wn + n*16 + lr;
      bfr[n] = *(const bf16x8*)(&Bs[buf][row*32 + (lk ^ (((row >> 1) & 3)*8))]);
    }
#pragma unroll
    for (int m = 0; m < 8; ++m) {
      int row = wm + m*16 + lr;
      af[m] = *(const bf16x8*)(&As[buf][row*32 + (lk ^ (((row >> 1) & 3)*8))]);
    }
#pragma unroll
    for (int m = 0; m < 8; ++m)
#pragma unroll
      for (int n = 0; n < 4; ++n)
        acc[m][n] = __builtin_amdgcn_mfma_f32_16x16x32_bf16(af[m], bfr[n], acc[m][n], 0, 0, 0);
    if (kt + 3 < nk) STAGE((kt + 3) & 3, kt + 3);
    __builtin_amdgcn_s_barrier();        // protect buf reuse next iterations
  }

  float bv[4];
#pragma unroll
  for (int n = 0; n < 4; ++n) bv[n] = bias[bx*256 + wn + n*16 + lr];
  const int r0 = (lane >> 4) * 4;

#pragma unroll
  for (int m = 0; m < 8; ++m) {
#pragma unroll
    for (int r = 0; r < 4; ++r) {
      const int rl = wm + m*16 + r0 + r;
      size_t row = (size_t)by*256 + rl;
      float v0 = acc[m][0][r] + bv[0], v1 = acc[m][1][r] + bv[1];
      float v2 = acc[m][2][r] + bv[2], v3 = acc[m][3][r] + bv[3];
      size_t cb = row*(size_t)N + (size_t)(bx*256 + wn + lr);
      __builtin_nontemporal_store(v0, &C[cb]);
      __builtin_nontemporal_store(v1, &C[cb + 16]);
      __builtin_nontemporal_store(v2, &C[cb + 32]);
      __builtin_nontemporal_store(v3, &C[cb + 48]);
      float mx = fmaxf(fmaxf(v0, v1), fmaxf(v2, v3));
#pragma unroll
      for (int o = 1; o <= 8; o <<= 1) mx = fmaxf(mx, __shfl_xor(mx, o));
      float s = __expf(v0-mx) + __expf(v1-mx) + __expf(v2-mx) + __expf(v3-mx);
#pragma unroll
      for (int o = 1; o <= 8; o <<= 1) s += __shfl_xor(s, o);
      if (lr == 0) { sm_m[wid & 3][rl] = mx; sm_s[wid & 3][rl] = s; }
    }
  }
  __syncthreads();
  if (tid < 256) {
    float m = -1e30f, s = 0.f;
#pragma unroll
    for (int c = 0; c < 4; ++c) {
      float mi = sm_m[c][tid], si = sm_s[c][tid];
      float nm = fmaxf(m, mi);
      s = s*__expf(m - nm) + si*__expf(mi - nm);
      m = nm;
    }
    size_t row = (size_t)by*256 + tid;
    pmax[row*NTB256 + bx] = m;
    psum[row*NTB256 + bx] = s;
  }
}

// ---------------- MFMA attention: causal softmax(QK^T/8)V per (b,h,qt) ------
__global__ __launch_bounds__(256) void attn_mfma(const bf16* __restrict__ qkv,
                                                 bf16* __restrict__ vals) {
  __shared__ __align__(16) ushort Ks[256*72];   // 36 KB, reused for P
  __shared__ __align__(16) ushort Vt[64*264];   // 33 KB
  const int tid = threadIdx.x;
  const int lane = tid & 63, w = tid >> 6;
  const int lo = lane & 15, hi = lane >> 4;
  const int bid = blockIdx.x;
  const int qt = bid & 3, bh = bid >> 2;
  const int b = bh / HSZ, hh = bh - b*HSZ;
  const int nkr = (qt + 1) * 64;          // staged K/V rows (max k+1)
  const int qb = qt*64 + w*16;            // wave's first q row (in sequence)
  const int ntile = qt*4 + w + 1;         // live 16-wide k-tiles for this wave
  const int kkmax = (ntile + 1) >> 1;     // 32-wide PV k-steps (pad to even)

  { // stage K rows [0,nkr): Ks[j][0..63], stride 72 elems
    const int jr = tid >> 3, cc = (tid & 7) * 8;
    for (int p = 0; p < (qt+1)*2; ++p) {
      int j = p*32 + jr;
      const bf16* base = qkv + ((size_t)(b*SSZ + j))*D3 + hh*192 + 64 + cc;
      uint4 kq = *(const uint4*)base;
      *(uint2*)(&Ks[j*72 + cc])     = make_uint2(kq.x, kq.y);
      *(uint2*)(&Ks[j*72 + cc + 4]) = make_uint2(kq.z, kq.w);
    }
  }
  // stage V transposed: Vt[d][k] = V[k][d], stride 264 elems
  for (int k = tid; k < nkr; k += 256) {
    const bf16* vrow = qkv + ((size_t)(b*SSZ + k))*D3 + hh*192 + 128;
#pragma unroll
    for (int c = 0; c < 8; ++c) {
      uint4 vv = *(const uint4*)(vrow + c*8);
      const ushort* u = (const ushort*)&vv;
#pragma unroll
      for (int j = 0; j < 8; ++j)
        Vt[(c*8 + j)*264 + k] = u[j];
    }
  }

  // Q fragments (A-operand): lane holds Q[qb+lo][hi*8 + kk*32 ..+7]
  bf16x8 qf0, qf1;
  {
    const bf16* qrow = qkv + ((size_t)(b*SSZ + qb + lo))*D3 + hh*192 + hi*8;
    qf0 = *(const bf16x8*)(qrow);
    qf1 = *(const bf16x8*)(qrow + 32);
  }
  __syncthreads();

  // ---- QK^T: S[16 x ntile*16]
  f32x4 zz = {0.f, 0.f, 0.f, 0.f};
  f32x4 sacc[16];
#pragma unroll
  for (int n = 0; n < 16; ++n) sacc[n] = zz;
#pragma unroll
  for (int n = 0; n < 16; ++n)
    if (n < ntile) {
      const bf16* kb0 = (const bf16*)&Ks[(n*16 + lo)*72 + hi*8];
      bf16x8 bf0 = *(const bf16x8*)(kb0);
      bf16x8 bf1 = *(const bf16x8*)(kb0 + 32);
      sacc[n] = __builtin_amdgcn_mfma_f32_16x16x32_bf16(qf0, bf0, sacc[n], 0, 0, 0);
      sacc[n] = __builtin_amdgcn_mfma_f32_16x16x32_bf16(qf1, bf1, sacc[n], 0, 0, 0);
    }
  __syncthreads();   // all waves done reading Ks; its space becomes P

  // ---- mask + scale + row max (rows hi*4+r, cols n*16+lo)
  float mrow[4] = {-1e30f, -1e30f, -1e30f, -1e30f};
#pragma unroll
  for (int n = 0; n < 16; ++n)
    if (n < ntile) {
#pragma unroll
      for (int r = 0; r < 4; ++r) {
        int kcol = n*16 + lo, qi = qb + hi*4 + r;
        float s = (kcol <= qi) ? sacc[n][r]*0.125f : -1e30f;
        sacc[n][r] = s;
        mrow[r] = fmaxf(mrow[r], s);
      }
    }
#pragma unroll
  for (int r = 0; r < 4; ++r)
#pragma unroll
    for (int o = 1; o <= 8; o <<= 1)
      mrow[r] = fmaxf(mrow[r], __shfl_xor(mrow[r], o));

  // ---- P = exp(S - m) -> bf16 in private LDS slab; row sums
  ushort* Pl = &Ks[w*64*72];   // 4608 ush >= 16 rows * 264
  float lsum[4] = {0.f, 0.f, 0.f, 0.f};
#pragma unroll
  for (int n = 0; n < 16; ++n)
    if (n < 2*kkmax) {
#pragma unroll
      for (int r = 0; r < 4; ++r) {
        float e = 0.f;
        if (n < ntile) { e = __expf(sacc[n][r] - mrow[r]); lsum[r] += e; }
        bf16 eb = (bf16)e;
        Pl[(hi*4 + r)*264 + n*16 + lo] = *(const ushort*)&eb;
      }
    }
#pragma unroll
  for (int r = 0; r < 4; ++r)
#pragma unroll
    for (int o = 1; o <= 8; o <<= 1)
      lsum[r] += __shfl_xor(lsum[r], o);

  asm volatile("s_waitcnt lgkmcnt(0)" ::: "memory"); // P visible wave-wide

  // ---- PV: O[16 x 64] += P * Vt
  f32x4 oacc[4];
#pragma unroll
  for (int nd = 0; nd < 4; ++nd) oacc[nd] = zz;
#pragma unroll
  for (int kk = 0; kk < 8; ++kk)
    if (kk < kkmax) {
      bf16x8 pf = *(const bf16x8*)((const bf16*)&Pl[lo*264 + kk*32 + hi*8]);
#pragma unroll
      for (int nd = 0; nd < 4; ++nd) {
        bf16x8 vf = *(const bf16x8*)((const bf16*)&Vt[(nd*16 + lo)*264 + kk*32 + hi*8]);
        oacc[nd] = __builtin_amdgcn_mfma_f32_16x16x32_bf16(pf, vf, oacc[nd], 0, 0, 0);
      }
    }

  // ---- epilogue: divide by row sum, write vals[row][hh*64 + d]
#pragma unroll
  for (int r = 0; r < 4; ++r) {
    float inv = 1.0f / lsum[r];
    size_t row = (size_t)(b*SSZ + qb + hi*4 + r);
#pragma unroll
    for (int nd = 0; nd < 4; ++nd)
      vals[row*DSZ + hh*64 + nd*16 + lo] = (bf16)(oacc[nd][r] * inv);
  }
}

// ---------------- merge per-tile LSE partials -> nll (wave per row) ---------
__global__ __launch_bounds__(256) void loss_merge(const float* __restrict__ pmax,
    const float* __restrict__ psum, const float* __restrict__ logits,
    const int* __restrict__ tg, float* __restrict__ nll, int ntb) {
  const int t = threadIdx.x;
  const int lane = t & 63, w = t >> 6;
  const int row = blockIdx.x*4 + w;
  float m = -1e30f, s = 0.f;
  for (int i = lane; i < ntb; i += 64) {
    float mi = pmax[(size_t)row*ntb + i], si = psum[(size_t)row*ntb + i];
    float nm = fmaxf(m, mi);
    s = s*__expf(m - nm) + si*__expf(mi - nm);
    m = nm;
  }
#pragma unroll
  for (int o = 32; o; o >>= 1) {
    float mo = __shfl_xor(m, o), so = __shfl_xor(s, o);
    float nm = fmaxf(m, mo);
    s = s*__expf(m - nm) + so*__expf(mo - nm);
    m = nm;
  }
  if (lane == 0)
    nll[row] = (m + logf(s)) - logits[(size_t)row*VSZ + tg[row]];
}

__global__ __launch_bounds__(256) void loss_final(const float* __restrict__ nll,
                                                  float* __restrict__ out) {
  __shared__ float red[4];
  const int t = threadIdx.x;
  const int lane = t & 63, w = t >> 6;
  float s = 0.f;
  for (int i = t; i < NROW; i += 256) s += nll[i];
#pragma unroll
  for (int o = 32; o; o >>= 1) s += __shfl_xor(s, o);
  if (lane == 0) red[w] = s;
  __syncthreads();
  if (t == 0) out[0] = (red[0]+red[1]+red[2]+red[3]) * (1.0f/NROW);
}

// ---------------------------------------------------------------------------
extern "C" void kernel_launch(void* const* d_in, const int* in_sizes, int n_in,
                              void* d_out, int out_size, void* d_ws, size_t ws_size,
                              hipStream_t stream) {
  (void)in_sizes; (void)n_in; (void)out_size; (void)ws_size;
  const int*   x       = (const int*)  d_in[0];
  const int*   targets = (const int*)  d_in[1];
  const float* emb     = (const float*)d_in[2];
  const float* Wqkv    = (const float*)d_in[3];
  const float* bqkv    = (const float*)d_in[4];
  const float* Wo      = (const float*)d_in[5];
  const float* bo      = (const float*)d_in[6];
  const float* gamma1  = (const float*)d_in[7];
  const float* beta1   = (const float*)d_in[8];
  const float* W1      = (const float*)d_in[9];
  const float* b1      = (const float*)d_in[10];
  const float* W2      = (const float*)d_in[11];
  const float* b2      = (const float*)d_in[12];
  const float* gamma2  = (const float*)d_in[13];
  const float* beta2   = (const float*)d_in[14];
  const float* Wout    = (const float*)d_in[15];
  const float* bout    = (const float*)d_in[16];
  float* out = (float*)d_out;

  char* wp = (char*)d_ws;
  auto carve = [&](size_t bytes)->char* {
    char* p = wp; wp += (bytes + 255) & ~(size_t)255; return p;
  };
  bf16*  Wqkv_b = (bf16*) carve((size_t)LSZ*D3*DSZ*2);
  bf16*  Wo_b   = (bf16*) carve((size_t)LSZ*DSZ*DSZ*2);
  bf16*  W1_b   = (bf16*) carve((size_t)LSZ*FHSZ*DSZ*2);
  bf16*  W2_b   = (bf16*) carve((size_t)LSZ*DSZ*FHSZ*2);
  bf16*  Wout_b = (bf16*) carve((size_t)VSZ*DSZ*2);
  float* h      = (float*)carve((size_t)NROW*DSZ*4);
  bf16*  hb     = (bf16*) carve((size_t)NROW*DSZ*2);
  bf16*  qkv_b  = (bf16*) carve((size_t)NROW*D3*2);
  bf16*  vals_b = (bf16*) carve((size_t)NROW*DSZ*2);
  bf16*  ffn1_b = (bf16*) carve((size_t)NROW*FHSZ*2);
  float* nll    = (float*)carve((size_t)NROW*4);
  float* pmax   = (float*)carve((size_t)NROW*NTB256*4);
  float* psum   = (float*)carve((size_t)NROW*NTB256*4);
  float* pe     = (float*)carve((size_t)SSZ*DSZ*4);

  // weights -> bf16 (one batched launch, NT loads)
  CvtDesc dd = { Wqkv, Wqkv_b, Wo, Wo_b, W1, W1_b, W2, W2_b, Wout, Wout_b };
  cvt_all<<<dim3(4096), dim3(256), 0, stream>>>(dd);

  pe_k<<<dim3(SSZ*DSZ/256), dim3(256), 0, stream>>>(pe);
  embed_k<<<dim3(2048), dim3(256), 0, stream>>>(x, emb, pe, h, hb);

  for (int l = 0; l < LSZ; ++l) {
    gemm_bt<1><<<dim3(D3/128, NROW/128), dim3(256), 0, stream>>>(
        hb, Wqkv_b + (size_t)l*D3*DSZ, bqkv + l*D3, qkv_b, D3, DSZ);
    attn_mfma<<<dim3(BSZ*HSZ*4), dim3(256), 0, stream>>>(qkv_b, vals_b);
    gemm_ln<DSZ><<<dim3(NROW/64), dim3(256), 0, stream>>>(
        vals_b, Wo_b + (size_t)l*DSZ*DSZ, bo + l*DSZ,
        gamma1 + l*DSZ, beta1 + l*DSZ, h, hb);
    gemm_bt<2><<<dim3(FHSZ/128, NROW/128), dim3(256), 0, stream>>>(
        hb, W1_b + (size_t)l*FHSZ*DSZ, b1 + l*FHSZ, ffn1_b, FHSZ, DSZ);
    gemm_ln<FHSZ><<<dim3(NROW/64), dim3(256), 0, stream>>>(
        ffn1_b, W2_b + (size_t)l*DSZ*FHSZ, b2 + l*DSZ,
        gamma2 + l*DSZ, beta2 + l*DSZ, h, hb);
  }

  gemm256_lse<<<dim3(VSZ/256, NROW/256), dim3(512), 0, stream>>>(
      hb, Wout_b, bout, out, pmax, psum);
  loss_merge<<<dim3(NROW/4), dim3(256), 0, stream>>>(pmax, psum, out, targets, nll, NTB256);
  loss_final<<<dim3(1), dim3(256), 0, stream>>>(nll, out + (size_t)NROW*VSZ);
}

// Round 14
// 1260.303 us; speedup vs baseline: 1.1534x; 1.1534x over previous
//
#include <hip/hip_runtime.h>
#include <hip/hip_bf16.h>
#include <math.h>

// Transformer forward, MI355X. Sizes fixed by the reference.
#define VSZ 32000
#define DSZ 384
#define HSZ 6
#define LSZ 6
#define FHSZ 1536
#define BSZ 38
#define SSZ 256
#define HDSZ 64
#define NROW (BSZ*SSZ)    // 9728
#define D3 (3*DSZ)        // 1152
#define NTB256 (VSZ/256)  // 125 logits col-tiles

typedef __bf16 bf16;
typedef __attribute__((ext_vector_type(8))) __bf16 bf16x8;
typedef __attribute__((ext_vector_type(4))) __bf16 bf16x4;
typedef __attribute__((ext_vector_type(4))) float f32x4;

__device__ __forceinline__ void gload16(const bf16* g, bf16* l) {
  __builtin_amdgcn_global_load_lds((const __attribute__((address_space(1))) void*)g,
                                   (__attribute__((address_space(3))) void*)l, 16, 0, 0);
}

// bijective XCD-chunked swizzle (m204)
__device__ __forceinline__ int xcd_swz(int orig, int nwg) {
  int q = nwg >> 3, r = nwg & 7;
  int xcd = orig & 7, lin = orig >> 3;
  return (xcd < r ? xcd*(q+1) : r*(q+1) + (xcd - r)*q) + lin;
}

// fast erf, Abramowitz-Stegun 7.1.26 (|err|<=1.5e-7, far below bf16 rounding)
__device__ __forceinline__ float fast_erf(float x) {
  float ax = fabsf(x);
  float t = 1.0f / fmaf(0.3275911f, ax, 1.0f);
  float p = fmaf(t, 1.061405429f, -1.453152027f);
  p = fmaf(p, t, 1.421413741f);
  p = fmaf(p, t, -0.284496736f);
  p = fmaf(p, t, 0.254829592f);
  float y = 1.0f - p*t*__expf(-ax*ax);
  return copysignf(y, x);
}

// ---------------- batched f32 -> bf16 weight convert (one launch) -----------
struct CvtDesc { const float* s0; bf16* d0; const float* s1; bf16* d1;
                 const float* s2; bf16* d2; const float* s3; bf16* d3;
                 const float* s4; bf16* d4; };
#define C0 663552   // Wqkv n4 end
#define C1 884736   // + Wo
#define C2 1769472  // + W1
#define C3 2654208  // + W2
#define C4 5726208  // + Wout
__global__ __launch_bounds__(256) void cvt_all(CvtDesc dd) {
  int i = blockIdx.x*256 + threadIdx.x;
  int st = gridDim.x*256;
  for (; i < C4; i += st) {
    const float* s; bf16* d; int o;
    if      (i < C0) { s = dd.s0; d = dd.d0; o = i; }
    else if (i < C1) { s = dd.s1; d = dd.d1; o = i - C0; }
    else if (i < C2) { s = dd.s2; d = dd.d2; o = i - C1; }
    else if (i < C3) { s = dd.s3; d = dd.d3; o = i - C2; }
    else             { s = dd.s4; d = dd.d4; o = i - C3; }
    f32x4 v = __builtin_nontemporal_load((const f32x4*)s + o);
    bf16x4 ov = { (bf16)v[0], (bf16)v[1], (bf16)v[2], (bf16)v[3] };
    *(bf16x4*)(d + 4*(size_t)o) = ov;
  }
}

// ---------------- positional-encoding table (256 x 384) ---------------------
__global__ __launch_bounds__(256) void pe_k(float* __restrict__ pe) {
  const float c = 2.0f/384.0f*13.287712379549449f; // *log2(10000)
  int i = blockIdx.x*256 + threadIdx.x;            // 384 blocks
  int s = i / DSZ, d = i - s*DSZ;
  int ii = d >> 1;
  float ang = (float)s * exp2f(-(float)ii * c);
  pe[i] = (d & 1) ? cosf(ang) : sinf(ang);
}

// ---------------- embedding + pos table (pure BW) ---------------------------
__global__ __launch_bounds__(256) void embed_k(const int* __restrict__ x,
    const float* __restrict__ emb, const float* __restrict__ pe,
    float* __restrict__ h, bf16* __restrict__ hb) {
  const float scale = 19.595917942265423f; // sqrt(384)
  int i4 = blockIdx.x*256 + threadIdx.x;
  int st = gridDim.x*256;
  for (; i4 < NROW*(DSZ/4); i4 += st) {
    int r = i4 / (DSZ/4), c4 = (i4 - r*(DSZ/4))*4;
    int tok = x[r];
    int s = r & (SSZ-1);
    f32x4 e = *((const f32x4*)(emb + (size_t)tok*DSZ + c4));
    f32x4 p = *((const f32x4*)(pe + (size_t)s*DSZ + c4));
    f32x4 v = { e[0]*scale + p[0], e[1]*scale + p[1],
                e[2]*scale + p[2], e[3]*scale + p[3] };
    *(f32x4*)(h + (size_t)i4*4) = v;
    bf16x4 o = { (bf16)v[0], (bf16)v[1], (bf16)v[2], (bf16)v[3] };
    *(bf16x4*)(hb + (size_t)i4*4) = o;
  }
}

// ---------------- 128x128 GEMM: C = A * B^T + bias (2-phase dbuf, T2 swz) ---
// MODE 1: bf16 out; 2: exact-GELU (fast_erf) then bf16 out.
template<int MODE>
__global__ __launch_bounds__(256) void gemm_bt(const bf16* __restrict__ A,
    const bf16* __restrict__ Bm, const float* __restrict__ bias,
    bf16* __restrict__ Cv, int N, int K) {
  __shared__ __align__(16) bf16 As[2][128*64];
  __shared__ __align__(16) bf16 Bs[2][128*64];
  const int tid = threadIdx.x;
  const int lane = tid & 63, wid = tid >> 6;

  const int GX = gridDim.x, GY = gridDim.y;
  int orig = blockIdx.y*GX + blockIdx.x;
  int swz = xcd_swz(orig, GX*GY);
  int by = swz / GX, bx = swz - (swz/GX)*GX;

  const int wm = (wid >> 1) * 64, wn = (wid & 1) * 64;
  const int lr = lane & 15, lk = (lane >> 4) * 8;
  const int sx = (lr & 7) * 8;  // per-lane XOR swizzle offset (elements)

  f32x4 acc[4][4];
  f32x4 zz = {0.f, 0.f, 0.f, 0.f};
#pragma unroll
  for (int m = 0; m < 4; ++m)
#pragma unroll
    for (int n = 0; n < 4; ++n) acc[m][n] = zz;

  const bf16* Ab = A + (size_t)by*128*K;
  const bf16* Bb = Bm + (size_t)bx*128*K;
  const int nk = K >> 6;

  auto STAGE = [&](int buf, int kt) {
#pragma unroll
    for (int c = 0; c < 4; ++c) {
      int chunk = c*256 + tid;
      int row = chunk >> 3, sub = chunk & 7;
      int scol = (sub ^ (row & 7)) * 8;   // pre-swizzled source chunk
      gload16(Ab + (size_t)row*K + kt*64 + scol, &As[buf][chunk*8]);
      gload16(Bb + (size_t)row*K + kt*64 + scol, &Bs[buf][chunk*8]);
    }
  };

  STAGE(0, 0);
  __syncthreads();
  int cur = 0;
  for (int kt = 0; kt < nk; ++kt) {
    if (kt + 1 < nk) STAGE(cur ^ 1, kt + 1);
#pragma unroll
    for (int kk = 0; kk < 2; ++kk) {
      bf16x8 af[4], bfr[4];
#pragma unroll
      for (int m = 0; m < 4; ++m)
        af[m] = *(const bf16x8*)(&As[cur][(wm + m*16 + lr)*64 + ((kk*32 + lk) ^ sx)]);
#pragma unroll
      for (int n = 0; n < 4; ++n)
        bfr[n] = *(const bf16x8*)(&Bs[cur][(wn + n*16 + lr)*64 + ((kk*32 + lk) ^ sx)]);
#pragma unroll
      for (int m = 0; m < 4; ++m)
#pragma unroll
        for (int n = 0; n < 4; ++n)
          acc[m][n] = __builtin_amdgcn_mfma_f32_16x16x32_bf16(af[m], bfr[n], acc[m][n], 0, 0, 0);
    }
    __syncthreads();
    cur ^= 1;
  }

  float bv[4];
#pragma unroll
  for (int n = 0; n < 4; ++n) bv[n] = bias[bx*128 + wn + n*16 + lr];
  const int r0 = (lane >> 4) * 4;
#pragma unroll
  for (int m = 0; m < 4; ++m) {
#pragma unroll
    for (int r = 0; r < 4; ++r) {
      size_t row = (size_t)by*128 + wm + m*16 + r0 + r;
#pragma unroll
      for (int n = 0; n < 4; ++n) {
        float v = acc[m][n][r] + bv[n];
        size_t ci = row*(size_t)N + (size_t)(bx*128 + wn + n*16 + lr);
        if (MODE == 1) Cv[ci] = (bf16)v;
        else {
          v = 0.5f*v*(1.0f + fast_erf(v*0.70710678118654752f));
          Cv[ci] = (bf16)v;
        }
      }
    }
  }
}

// ---------------- split-K 128x128 GEMM -> bf16 partial slices ---------------
// Slice s covers K/NS; writes P[s*NROW*N + ci] as bf16 (halves slice traffic).
// Slice 0 adds bias.
template<int NS>
__global__ __launch_bounds__(256) void gemm_sk(const bf16* __restrict__ A,
    const bf16* __restrict__ Bm, const float* __restrict__ bias,
    bf16* __restrict__ P, int N, int K) {
  __shared__ __align__(16) bf16 As[2][128*64];
  __shared__ __align__(16) bf16 Bs[2][128*64];
  const int tid = threadIdx.x;
  const int lane = tid & 63, wid = tid >> 6;
  const int slice = blockIdx.z;
  const int Ksl = K / NS, kb = slice * Ksl;

  const int GX = gridDim.x, GY = gridDim.y;
  int orig = blockIdx.y*GX + blockIdx.x;
  int swz = xcd_swz(orig, GX*GY);
  int by = swz / GX, bx = swz - (swz/GX)*GX;

  const int wm = (wid >> 1) * 64, wn = (wid & 1) * 64;
  const int lr = lane & 15, lk = (lane >> 4) * 8;
  const int sx = (lr & 7) * 8;

  f32x4 acc[4][4];
  f32x4 zz = {0.f, 0.f, 0.f, 0.f};
#pragma unroll
  for (int m = 0; m < 4; ++m)
#pragma unroll
    for (int n = 0; n < 4; ++n) acc[m][n] = zz;

  const bf16* Ab = A + (size_t)by*128*K + kb;
  const bf16* Bb = Bm + (size_t)bx*128*K + kb;
  const int nk = Ksl >> 6;

  auto STAGE = [&](int buf, int kt) {
#pragma unroll
    for (int c = 0; c < 4; ++c) {
      int chunk = c*256 + tid;
      int row = chunk >> 3, sub = chunk & 7;
      int scol = (sub ^ (row & 7)) * 8;
      gload16(Ab + (size_t)row*K + kt*64 + scol, &As[buf][chunk*8]);
      gload16(Bb + (size_t)row*K + kt*64 + scol, &Bs[buf][chunk*8]);
    }
  };

  STAGE(0, 0);
  __syncthreads();
  int cur = 0;
  for (int kt = 0; kt < nk; ++kt) {
    if (kt + 1 < nk) STAGE(cur ^ 1, kt + 1);
#pragma unroll
    for (int kk = 0; kk < 2; ++kk) {
      bf16x8 af[4], bfr[4];
#pragma unroll
      for (int m = 0; m < 4; ++m)
        af[m] = *(const bf16x8*)(&As[cur][(wm + m*16 + lr)*64 + ((kk*32 + lk) ^ sx)]);
#pragma unroll
      for (int n = 0; n < 4; ++n)
        bfr[n] = *(const bf16x8*)(&Bs[cur][(wn + n*16 + lr)*64 + ((kk*32 + lk) ^ sx)]);
#pragma unroll
      for (int m = 0; m < 4; ++m)
#pragma unroll
        for (int n = 0; n < 4; ++n)
          acc[m][n] = __builtin_amdgcn_mfma_f32_16x16x32_bf16(af[m], bfr[n], acc[m][n], 0, 0, 0);
    }
    __syncthreads();
    cur ^= 1;
  }

  float bv[4];
#pragma unroll
  for (int n = 0; n < 4; ++n)
    bv[n] = (slice == 0) ? bias[bx*128 + wn + n*16 + lr] : 0.0f;
  const int r0 = (lane >> 4) * 4;
  bf16* Pw = P + (size_t)slice*NROW*N;
#pragma unroll
  for (int m = 0; m < 4; ++m) {
#pragma unroll
    for (int r = 0; r < 4; ++r) {
      size_t row = (size_t)by*128 + wm + m*16 + r0 + r;
#pragma unroll
      for (int n = 0; n < 4; ++n) {
        size_t ci = row*(size_t)N + (size_t)(bx*128 + wn + n*16 + lr);
        Pw[ci] = (bf16)(acc[m][n][r] + bv[n]);
      }
    }
  }
}

// ---------------- 256x256 logits GEMM + fused LSE partials ------------------
// BK=32, 4 LDS buffers, 3-deep counted-vmcnt pipeline (T4).
__global__ __launch_bounds__(512, 2) void gemm256_lse(const bf16* __restrict__ A,
    const bf16* __restrict__ Bm, const float* __restrict__ bias,
    float* __restrict__ C, float* __restrict__ pmax, float* __restrict__ psum) {
  __shared__ __align__(16) bf16 As[4][256*32];   // 64 KB
  __shared__ __align__(16) bf16 Bs[4][256*32];   // 64 KB
  __shared__ float sm_m[4][256], sm_s[4][256];   // 8 KB
  const int K = DSZ, N = VSZ;
  const int tid = threadIdx.x;
  const int lane = tid & 63, wid = tid >> 6;

  const int GX = gridDim.x, GY = gridDim.y;   // (125, 38)
  int orig = blockIdx.y*GX + blockIdx.x;
  int swz = xcd_swz(orig, GX*GY);
  int bx = swz / GY, by = swz - (swz/GY)*GY;  // col-major: B-panel hot per XCD

  const int wm = (wid >> 2) * 128, wn = (wid & 3) * 64;
  const int lr = lane & 15, lk = (lane >> 4) * 8;  // lk in {0,8,16,24}

  f32x4 acc[8][4];
  f32x4 zz = {0.f, 0.f, 0.f, 0.f};
#pragma unroll
  for (int m = 0; m < 8; ++m)
#pragma unroll
    for (int n = 0; n < 4; ++n) acc[m][n] = zz;

  const bf16* Ab = A + (size_t)by*256*K;
  const bf16* Bb = Bm + (size_t)bx*256*K;
  const int nk = 12;  // K=384 / BK=32

  auto STAGE = [&](int buf, int kt) {
#pragma unroll
    for (int c = 0; c < 2; ++c) {
      int chunk = c*512 + tid;           // 1024 chunks = 256 rows x 4 sub
      int row = chunk >> 2, sub = chunk & 3;
      int scol = (sub ^ ((row >> 1) & 3)) * 8;   // inverse-swizzled source
      gload16(Ab + (size_t)row*K + kt*32 + scol, &As[buf][chunk*8]);
      gload16(Bb + (size_t)row*K + kt*32 + scol, &Bs[buf][chunk*8]);
    }
  };

  STAGE(0, 0); STAGE(1, 1); STAGE(2, 2);   // 12 loads/thread in flight
  for (int kt = 0; kt < nk; ++kt) {
    if (kt < nk - 2)      asm volatile("s_waitcnt vmcnt(8)" ::: "memory");
    else if (kt == nk-2)  asm volatile("s_waitcnt vmcnt(4)" ::: "memory");
    else                  asm volatile("s_waitcnt vmcnt(0)" ::: "memory");
    __builtin_amdgcn_s_barrier();
    __builtin_amdgcn_sched_barrier(0);   // rule 18: no ds_read hoist above bar
    const int buf = kt & 3;
    bf16x8 af[8], bfr[4];
#pragma unroll
    for (int n = 0; n < 4; ++n) {
      int row = wn + n*16 + lr;
      bfr[n] = *(const bf16x8*)(&Bs[buf][row*32 + (lk ^ (((row >> 1) & 3)*8))]);
    }
#pragma unroll
    for (int m = 0; m < 8; ++m) {
      int row = wm + m*16 + lr;
      af[m] = *(const bf16x8*)(&As[buf][row*32 + (lk ^ (((row >> 1) & 3)*8))]);
    }
#pragma unroll
    for (int m = 0; m < 8; ++m)
#pragma unroll
      for (int n = 0; n < 4; ++n)
        acc[m][n] = __builtin_amdgcn_mfma_f32_16x16x32_bf16(af[m], bfr[n], acc[m][n], 0, 0, 0);
    if (kt + 3 < nk) STAGE((kt + 3) & 3, kt + 3);
    __builtin_amdgcn_s_barrier();        // protect buf reuse next iterations
  }

  float bv[4];
#pragma unroll
  for (int n = 0; n < 4; ++n) bv[n] = bias[bx*256 + wn + n*16 + lr];
  const int r0 = (lane >> 4) * 4;

#pragma unroll
  for (int m = 0; m < 8; ++m) {
#pragma unroll
    for (int r = 0; r < 4; ++r) {
      const int rl = wm + m*16 + r0 + r;
      size_t row = (size_t)by*256 + rl;
      float v0 = acc[m][0][r] + bv[0], v1 = acc[m][1][r] + bv[1];
      float v2 = acc[m][2][r] + bv[2], v3 = acc[m][3][r] + bv[3];
      size_t cb = row*(size_t)N + (size_t)(bx*256 + wn + lr);
      __builtin_nontemporal_store(v0, &C[cb]);
      __builtin_nontemporal_store(v1, &C[cb + 16]);
      __builtin_nontemporal_store(v2, &C[cb + 32]);
      __builtin_nontemporal_store(v3, &C[cb + 48]);
      float mx = fmaxf(fmaxf(v0, v1), fmaxf(v2, v3));
#pragma unroll
      for (int o = 1; o <= 8; o <<= 1) mx = fmaxf(mx, __shfl_xor(mx, o));
      float s = __expf(v0-mx) + __expf(v1-mx) + __expf(v2-mx) + __expf(v3-mx);
#pragma unroll
      for (int o = 1; o <= 8; o <<= 1) s += __shfl_xor(s, o);
      if (lr == 0) { sm_m[wid & 3][rl] = mx; sm_s[wid & 3][rl] = s; }
    }
  }
  __syncthreads();
  if (tid < 256) {
    float m = -1e30f, s = 0.f;
#pragma unroll
    for (int c = 0; c < 4; ++c) {
      float mi = sm_m[c][tid], si = sm_s[c][tid];
      float nm = fmaxf(m, mi);
      s = s*__expf(m - nm) + si*__expf(mi - nm);
      m = nm;
    }
    size_t row = (size_t)by*256 + tid;
    pmax[row*NTB256 + bx] = m;
    psum[row*NTB256 + bx] = s;
  }
}

// ---------------- MFMA attention: causal softmax(QK^T/8)V per (b,h,qt) ------
__global__ __launch_bounds__(256) void attn_mfma(const bf16* __restrict__ qkv,
                                                 bf16* __restrict__ vals) {
  __shared__ __align__(16) ushort Ks[256*72];   // 36 KB, reused for P
  __shared__ __align__(16) ushort Vt[64*264];   // 33 KB
  const int tid = threadIdx.x;
  const int lane = tid & 63, w = tid >> 6;
  const int lo = lane & 15, hi = lane >> 4;
  const int bid = blockIdx.x;
  const int qt = bid & 3, bh = bid >> 2;
  const int b = bh / HSZ, hh = bh - b*HSZ;
  const int nkr = (qt + 1) * 64;          // staged K/V rows (max k+1)
  const int qb = qt*64 + w*16;            // wave's first q row (in sequence)
  const int ntile = qt*4 + w + 1;         // live 16-wide k-tiles for this wave
  const int kkmax = (ntile + 1) >> 1;     // 32-wide PV k-steps (pad to even)

  { // stage K rows [0,nkr): Ks[j][0..63], stride 72 elems
    const int jr = tid >> 3, cc = (tid & 7) * 8;
    for (int p = 0; p < (qt+1)*2; ++p) {
      int j = p*32 + jr;
      const bf16* base = qkv + ((size_t)(b*SSZ + j))*D3 + hh*192 + 64 + cc;
      uint4 kq = *(const uint4*)base;
      *(uint2*)(&Ks[j*72 + cc])     = make_uint2(kq.x, kq.y);
      *(uint2*)(&Ks[j*72 + cc + 4]) = make_uint2(kq.z, kq.w);
    }
  }
  // stage V transposed: Vt[d][k] = V[k][d], stride 264 elems
  for (int k = tid; k < nkr; k += 256) {
    const bf16* vrow = qkv + ((size_t)(b*SSZ + k))*D3 + hh*192 + 128;
#pragma unroll
    for (int c = 0; c < 8; ++c) {
      uint4 vv = *(const uint4*)(vrow + c*8);
      const ushort* u = (const ushort*)&vv;
#pragma unroll
      for (int j = 0; j < 8; ++j)
        Vt[(c*8 + j)*264 + k] = u[j];
    }
  }

  // Q fragments (A-operand): lane holds Q[qb+lo][hi*8 + kk*32 ..+7]
  bf16x8 qf0, qf1;
  {
    const bf16* qrow = qkv + ((size_t)(b*SSZ + qb + lo))*D3 + hh*192 + hi*8;
    qf0 = *(const bf16x8*)(qrow);
    qf1 = *(const bf16x8*)(qrow + 32);
  }
  __syncthreads();

  // ---- QK^T: S[16 x ntile*16]
  f32x4 zz = {0.f, 0.f, 0.f, 0.f};
  f32x4 sacc[16];
#pragma unroll
  for (int n = 0; n < 16; ++n) sacc[n] = zz;
#pragma unroll
  for (int n = 0; n < 16; ++n)
    if (n < ntile) {
      const bf16* kb0 = (const bf16*)&Ks[(n*16 + lo)*72 + hi*8];
      bf16x8 bf0 = *(const bf16x8*)(kb0);
      bf16x8 bf1 = *(const bf16x8*)(kb0 + 32);
      sacc[n] = __builtin_amdgcn_mfma_f32_16x16x32_bf16(qf0, bf0, sacc[n], 0, 0, 0);
      sacc[n] = __builtin_amdgcn_mfma_f32_16x16x32_bf16(qf1, bf1, sacc[n], 0, 0, 0);
    }
  __syncthreads();   // all waves done reading Ks; its space becomes P

  // ---- mask + scale + row max (rows hi*4+r, cols n*16+lo)
  float mrow[4] = {-1e30f, -1e30f, -1e30f, -1e30f};
#pragma unroll
  for (int n = 0; n < 16; ++n)
    if (n < ntile) {
#pragma unroll
      for (int r = 0; r < 4; ++r) {
        int kcol = n*16 + lo, qi = qb + hi*4 + r;
        float s = (kcol <= qi) ? sacc[n][r]*0.125f : -1e30f;
        sacc[n][r] = s;
        mrow[r] = fmaxf(mrow[r], s);
      }
    }
#pragma unroll
  for (int r = 0; r < 4; ++r)
#pragma unroll
    for (int o = 1; o <= 8; o <<= 1)
      mrow[r] = fmaxf(mrow[r], __shfl_xor(mrow[r], o));

  // ---- P = exp(S - m) -> bf16 in private LDS slab; row sums
  ushort* Pl = &Ks[w*64*72];   // 4608 ush >= 16 rows * 264
  float lsum[4] = {0.f, 0.f, 0.f, 0.f};
#pragma unroll
  for (int n = 0; n < 16; ++n)
    if (n < 2*kkmax) {
#pragma unroll
      for (int r = 0; r < 4; ++r) {
        float e = 0.f;
        if (n < ntile) { e = __expf(sacc[n][r] - mrow[r]); lsum[r] += e; }
        bf16 eb = (bf16)e;
        Pl[(hi*4 + r)*264 + n*16 + lo] = *(const ushort*)&eb;
      }
    }
#pragma unroll
  for (int r = 0; r < 4; ++r)
#pragma unroll
    for (int o = 1; o <= 8; o <<= 1)
      lsum[r] += __shfl_xor(lsum[r], o);

  asm volatile("s_waitcnt lgkmcnt(0)" ::: "memory"); // P visible wave-wide

  // ---- PV: O[16 x 64] += P * Vt
  f32x4 oacc[4];
#pragma unroll
  for (int nd = 0; nd < 4; ++nd) oacc[nd] = zz;
#pragma unroll
  for (int kk = 0; kk < 8; ++kk)
    if (kk < kkmax) {
      bf16x8 pf = *(const bf16x8*)((const bf16*)&Pl[lo*264 + kk*32 + hi*8]);
#pragma unroll
      for (int nd = 0; nd < 4; ++nd) {
        bf16x8 vf = *(const bf16x8*)((const bf16*)&Vt[(nd*16 + lo)*264 + kk*32 + hi*8]);
        oacc[nd] = __builtin_amdgcn_mfma_f32_16x16x32_bf16(pf, vf, oacc[nd], 0, 0, 0);
      }
    }

  // ---- epilogue: divide by row sum, write vals[row][hh*64 + d]
#pragma unroll
  for (int r = 0; r < 4; ++r) {
    float inv = 1.0f / lsum[r];
    size_t row = (size_t)(b*SSZ + qb + hi*4 + r);
#pragma unroll
    for (int nd = 0; nd < 4; ++nd)
      vals[row*DSZ + hh*64 + nd*16 + lo] = (bf16)(oacc[nd][r] * inv);
  }
}

// ---------------- residual + bf16 split-K partial sum + layernorm -----------
// v = h + sum_s P[s]; h = LN(v); hb = bf16(h). One wave per row.
template<int NS>
__global__ __launch_bounds__(256) void ln_sum(const bf16* __restrict__ P,
    const float* __restrict__ gamma, const float* __restrict__ beta,
    float* __restrict__ h, bf16* __restrict__ hb) {
  const int t = threadIdx.x;
  const int lane = t & 63, w = t >> 6;
  const int row = blockIdx.x*4 + w;
  const size_t base = (size_t)row*DSZ;
  float v[6];
  float s = 0.f;
#pragma unroll
  for (int k = 0; k < 6; ++k) {
    int idx = lane + k*64;
    float acc = h[base + idx];
#pragma unroll
    for (int sl = 0; sl < NS; ++sl)
      acc += (float)P[(size_t)sl*NROW*DSZ + base + idx];
    v[k] = acc;
    s += acc;
  }
#pragma unroll
  for (int o = 32; o; o >>= 1) s += __shfl_xor(s, o);
  float mean = s * (1.0f/DSZ);
  float s2 = 0.f;
#pragma unroll
  for (int k = 0; k < 6; ++k) { float dv = v[k] - mean; s2 += dv*dv; }
#pragma unroll
  for (int o = 32; o; o >>= 1) s2 += __shfl_xor(s2, o);
  float rstd = rsqrtf(s2 * (1.0f/DSZ) + 1e-5f);
#pragma unroll
  for (int k = 0; k < 6; ++k) {
    int idx = lane + k*64;
    float outv = gamma[idx]*(v[k] - mean)*rstd + beta[idx];
    h[base + idx] = outv;
    hb[base + idx] = (bf16)outv;
  }
}

// ---------------- merge per-tile LSE partials -> nll (wave per row) ---------
__global__ __launch_bounds__(256) void loss_merge(const float* __restrict__ pmax,
    const float* __restrict__ psum, const float* __restrict__ logits,
    const int* __restrict__ tg, float* __restrict__ nll, int ntb) {
  const int t = threadIdx.x;
  const int lane = t & 63, w = t >> 6;
  const int row = blockIdx.x*4 + w;
  float m = -1e30f, s = 0.f;
  for (int i = lane; i < ntb; i += 64) {
    float mi = pmax[(size_t)row*ntb + i], si = psum[(size_t)row*ntb + i];
    float nm = fmaxf(m, mi);
    s = s*__expf(m - nm) + si*__expf(mi - nm);
    m = nm;
  }
#pragma unroll
  for (int o = 32; o; o >>= 1) {
    float mo = __shfl_xor(m, o), so = __shfl_xor(s, o);
    float nm = fmaxf(m, mo);
    s = s*__expf(m - nm) + so*__expf(mo - nm);
    m = nm;
  }
  if (lane == 0)
    nll[row] = (m + logf(s)) - logits[(size_t)row*VSZ + tg[row]];
}

__global__ __launch_bounds__(256) void loss_final(const float* __restrict__ nll,
                                                  float* __restrict__ out) {
  __shared__ float red[4];
  const int t = threadIdx.x;
  const int lane = t & 63, w = t >> 6;
  float s = 0.f;
  for (int i = t; i < NROW; i += 256) s += nll[i];
#pragma unroll
  for (int o = 32; o; o >>= 1) s += __shfl_xor(s, o);
  if (lane == 0) red[w] = s;
  __syncthreads();
  if (t == 0) out[0] = (red[0]+red[1]+red[2]+red[3]) * (1.0f/NROW);
}

// ---------------------------------------------------------------------------
extern "C" void kernel_launch(void* const* d_in, const int* in_sizes, int n_in,
                              void* d_out, int out_size, void* d_ws, size_t ws_size,
                              hipStream_t stream) {
  (void)in_sizes; (void)n_in; (void)out_size; (void)ws_size;
  const int*   x       = (const int*)  d_in[0];
  const int*   targets = (const int*)  d_in[1];
  const float* emb     = (const float*)d_in[2];
  const float* Wqkv    = (const float*)d_in[3];
  const float* bqkv    = (const float*)d_in[4];
  const float* Wo      = (const float*)d_in[5];
  const float* bo      = (const float*)d_in[6];
  const float* gamma1  = (const float*)d_in[7];
  const float* beta1   = (const float*)d_in[8];
  const float* W1      = (const float*)d_in[9];
  const float* b1      = (const float*)d_in[10];
  const float* W2      = (const float*)d_in[11];
  const float* b2      = (const float*)d_in[12];
  const float* gamma2  = (const float*)d_in[13];
  const float* beta2   = (const float*)d_in[14];
  const float* Wout    = (const float*)d_in[15];
  const float* bout    = (const float*)d_in[16];
  float* out = (float*)d_out;

  char* wp = (char*)d_ws;
  auto carve = [&](size_t bytes)->char* {
    char* p = wp; wp += (bytes + 255) & ~(size_t)255; return p;
  };
  bf16*  Wqkv_b = (bf16*) carve((size_t)LSZ*D3*DSZ*2);
  bf16*  Wo_b   = (bf16*) carve((size_t)LSZ*DSZ*DSZ*2);
  bf16*  W1_b   = (bf16*) carve((size_t)LSZ*FHSZ*DSZ*2);
  bf16*  W2_b   = (bf16*) carve((size_t)LSZ*DSZ*FHSZ*2);
  bf16*  Wout_b = (bf16*) carve((size_t)VSZ*DSZ*2);
  float* h      = (float*)carve((size_t)NROW*DSZ*4);
  bf16*  hb     = (bf16*) carve((size_t)NROW*DSZ*2);
  bf16*  qkv_b  = (bf16*) carve((size_t)NROW*D3*2);
  bf16*  vals_b = (bf16*) carve((size_t)NROW*DSZ*2);
  bf16*  tmp    = (bf16*) carve((size_t)4*NROW*DSZ*2);  // 4 bf16 split-K slices
  bf16*  ffn1_b = (bf16*) carve((size_t)NROW*FHSZ*2);
  float* nll    = (float*)carve((size_t)NROW*4);
  float* pmax   = (float*)carve((size_t)NROW*NTB256*4);
  float* psum   = (float*)carve((size_t)NROW*NTB256*4);
  float* pe     = (float*)carve((size_t)SSZ*DSZ*4);

  // weights -> bf16 (one batched launch, NT loads)
  CvtDesc dd = { Wqkv, Wqkv_b, Wo, Wo_b, W1, W1_b, W2, W2_b, Wout, Wout_b };
  cvt_all<<<dim3(4096), dim3(256), 0, stream>>>(dd);

  pe_k<<<dim3(SSZ*DSZ/256), dim3(256), 0, stream>>>(pe);
  embed_k<<<dim3(2048), dim3(256), 0, stream>>>(x, emb, pe, h, hb);

  for (int l = 0; l < LSZ; ++l) {
    gemm_bt<1><<<dim3(D3/128, NROW/128), dim3(256), 0, stream>>>(
        hb, Wqkv_b + (size_t)l*D3*DSZ, bqkv + l*D3, qkv_b, D3, DSZ);
    attn_mfma<<<dim3(BSZ*HSZ*4), dim3(256), 0, stream>>>(qkv_b, vals_b);
    gemm_sk<2><<<dim3(DSZ/128, NROW/128, 2), dim3(256), 0, stream>>>(
        vals_b, Wo_b + (size_t)l*DSZ*DSZ, bo + l*DSZ, tmp, DSZ, DSZ);
    ln_sum<2><<<dim3(NROW/4), dim3(256), 0, stream>>>(
        tmp, gamma1 + l*DSZ, beta1 + l*DSZ, h, hb);
    gemm_bt<2><<<dim3(FHSZ/128, NROW/128), dim3(256), 0, stream>>>(
        hb, W1_b + (size_t)l*FHSZ*DSZ, b1 + l*FHSZ, ffn1_b, FHSZ, DSZ);
    gemm_sk<4><<<dim3(DSZ/128, NROW/128, 4), dim3(256), 0, stream>>>(
        ffn1_b, W2_b + (size_t)l*DSZ*FHSZ, b2 + l*DSZ, tmp, DSZ, FHSZ);
    ln_sum<4><<<dim3(NROW/4), dim3(256), 0, stream>>>(
        tmp, gamma2 + l*DSZ, beta2 + l*DSZ, h, hb);
  }

  gemm256_lse<<<dim3(VSZ/256, NROW/256), dim3(512), 0, stream>>>(
      hb, Wout_b, bout, out, pmax, psum);
  loss_merge<<<dim3(NROW/4), dim3(256), 0, stream>>>(pmax, psum, out, targets, nll, NTB256);
  loss_final<<<dim3(1), dim3(256), 0, stream>>>(nll, out + (size_t)NROW*VSZ);
}